// Round 4
// baseline (315.799 us; speedup 1.0000x reference)
//
#include <hip/hip_runtime.h>
#include <hip/hip_bf16.h>

#define NB 4
#define NS 2048
#define ND 1024
#define NH 16
#define NHD 64
#define NM (NB*NS)   // 8192 rows of X

typedef __bf16 bf16_t;
typedef bf16_t bf8  __attribute__((ext_vector_type(8)));
typedef bf16_t bf4v __attribute__((ext_vector_type(4)));
typedef float  f4   __attribute__((ext_vector_type(4)));

// async global -> LDS, 16B per lane (dest = wave-uniform base + lane*16)
#define GLDS16(g, l) __builtin_amdgcn_global_load_lds( \
    (const __attribute__((address_space(1))) void*)(g), \
    (__attribute__((address_space(3))) void*)(l), 16, 0, 0)

// ---------------- fused fp32 -> bf16 conversion (X + 4 weights, one launch) ----
__global__ __launch_bounds__(256) void cvt_all(const float* __restrict__ x,
                                               const float* __restrict__ wq,
                                               const float* __restrict__ wk,
                                               const float* __restrict__ wv,
                                               const float* __restrict__ wo,
                                               bf16_t* __restrict__ Xb,
                                               bf16_t* __restrict__ Wqkv,
                                               bf16_t* __restrict__ Wob) {
    const int i = blockIdx.x * 256 + threadIdx.x;   // float4 index, total 3145728
    const float* src;
    bf16_t* dst;
    int off;
    if (i < 2097152) {            // X: 8192*1024 floats = 2097152 float4
        src = x; dst = Xb; off = i;
    } else {
        const int j = i - 2097152;        // [0, 4*262144)
        const int w = j >> 18;            // which weight
        off = j & 262143;
        src = (w == 0 ? wq : w == 1 ? wk : w == 2 ? wv : wo);
        dst = (w == 3 ? Wob : Wqkv + ((size_t)w << 20));
    }
    const float4 v = ((const float4*)src)[off];
    bf4v o;
    o[0] = (bf16_t)v.x; o[1] = (bf16_t)v.y; o[2] = (bf16_t)v.z; o[3] = (bf16_t)v.w;
    ((bf4v*)dst)[off] = o;
}

// ---------------- fused QKV GEMM (m97 structure: linear LDS + global_load_lds) ----
__global__ __launch_bounds__(256) void gemm_qkv(const bf16_t* __restrict__ A,
                                                const bf16_t* __restrict__ Bw,
                                                const float* __restrict__ bq,
                                                const float* __restrict__ bk,
                                                const float* __restrict__ bv,
                                                bf16_t* __restrict__ Qh,
                                                bf16_t* __restrict__ Kh,
                                                bf16_t* __restrict__ Vh) {
    __shared__ __align__(16) bf16_t As[128 * 32];
    __shared__ __align__(16) bf16_t Bs[128 * 32];
    const int t = threadIdx.x;
    const int wave = t >> 6, lane = t & 63, ln = lane & 15, quad = lane >> 4;
    const int wm = (wave >> 1) * 64, wn = (wave & 1) * 64;
    const int m0 = blockIdx.y * 128, n0 = blockIdx.x * 128;
    const int K = 1024;

    f4 acc[4][4];
    const f4 z = {0.f, 0.f, 0.f, 0.f};
#pragma unroll
    for (int i = 0; i < 4; ++i)
#pragma unroll
        for (int j = 0; j < 4; ++j) acc[i][j] = z;

    const int srow = wave * 16 + (lane >> 2);
    const int scol = (lane & 3) * 8;
    const bf16_t* Ag0 = A  + (size_t)(m0 + srow) * K + scol;
    const bf16_t* Ag1 = A  + (size_t)(m0 + srow + 64) * K + scol;
    const bf16_t* Bg0 = Bw + (size_t)(n0 + srow) * K + scol;
    const bf16_t* Bg1 = Bw + (size_t)(n0 + srow + 64) * K + scol;
    bf16_t* Al0 = &As[srow * 32 + scol];
    bf16_t* Al1 = &As[(srow + 64) * 32 + scol];
    bf16_t* Bl0 = &Bs[srow * 32 + scol];
    bf16_t* Bl1 = &Bs[(srow + 64) * 32 + scol];

    for (int k0 = 0; k0 < K; k0 += 32) {
        __syncthreads();
        GLDS16(Ag0 + k0, Al0);
        GLDS16(Ag1 + k0, Al1);
        GLDS16(Bg0 + k0, Bl0);
        GLDS16(Bg1 + k0, Bl1);
        __syncthreads();
        bf8 af[4], bfr[4];
#pragma unroll
        for (int mt = 0; mt < 4; ++mt) af[mt]  = *(const bf8*)(&As[(wm + mt * 16 + ln) * 32 + quad * 8]);
#pragma unroll
        for (int nt = 0; nt < 4; ++nt) bfr[nt] = *(const bf8*)(&Bs[(wn + nt * 16 + ln) * 32 + quad * 8]);
#pragma unroll
        for (int mt = 0; mt < 4; ++mt)
#pragma unroll
            for (int nt = 0; nt < 4; ++nt)
                acc[mt][nt] = __builtin_amdgcn_mfma_f32_16x16x32_bf16(af[mt], bfr[nt], acc[mt][nt], 0, 0, 0);
    }

#pragma unroll
    for (int nt = 0; nt < 4; ++nt) {
        const int gn = n0 + wn + nt * 16 + ln;
        const int sec = gn >> 10, nn = gn & 1023;
        const int h = nn >> 6, d = nn & 63;
        const float bias = (sec == 0 ? bq[nn] : (sec == 1 ? bk[nn] : bv[nn]));
        bf16_t* dstBase = (sec == 0 ? Qh : (sec == 1 ? Kh : Vh));
#pragma unroll
        for (int mt = 0; mt < 4; ++mt) {
#pragma unroll
            for (int r = 0; r < 4; ++r) {
                const int gm = m0 + wm + mt * 16 + quad * 4 + r;
                const int b = gm >> 11, s = gm & 2047;
                dstBase[((size_t)(b * NH + h) * NS + s) * NHD + d] = (bf16_t)(acc[mt][nt][r] + bias);
            }
        }
    }
}

// ---------------- flash attention ----------------
// v5: Q-block 128 (4 waves x 2 q-strips -> staged K/V tile feeds 2x compute),
// double-buffered K/V LDS (1 barrier/iter, commit overlaps PV), no manual
// lgkm drain (compiler tracks Ps aliasing). Inherited from v4: XCD head
// mapping, LPT, fixed m=0 softmax with deferred per-lane row sums,
// conflict-free transposed V staging, wave-private swizzled P strip,
// register prefetch (16 VGPR/thread), setprio around MFMA clusters.
__global__ __launch_bounds__(256) void attn_kernel(const bf16_t* __restrict__ Q,
                                                   const bf16_t* __restrict__ K,
                                                   const bf16_t* __restrict__ V,
                                                   bf16_t* __restrict__ O) {
    __shared__ __align__(16) bf16_t Ks[2][64 * 72];    // [buf][kv][d]
    __shared__ __align__(16) bf16_t Vt[2][64 * 72];    // [buf][d][kv]
    __shared__ __align__(16) bf16_t Ps[4][16 * 72];    // per-wave P strip
    const int L = blockIdx.x;                          // 1024 blocks
    const int mm = L >> 3;
    const int h  = ((mm >> 4) << 3) | (L & 7);         // head 0..63; XCD = L&7
    const int qt = 15 - (mm & 15);                     // LPT: longest first
    const int q0 = qt * 128;
    const int jmax  = 2 * qt + 1;                      // last KV tile (strip1)
    const int j0max = 2 * qt;                          // last KV tile (strip0)
    const size_t head_off = (size_t)h * NS * NHD;
    const int t = threadIdx.x;
    const int wave = t >> 6, lane = t & 63, ln = lane & 15, quad = lane >> 4;

    // Q fragments for both strips, 1/sqrt(hd)=0.125 folded in (exact in bf16)
    const bf16_t* Qrow0 = Q + head_off + (size_t)(q0 + wave * 16 + ln) * NHD;
    const bf16_t* Qrow1 = Qrow0 + (size_t)64 * NHD;
    bf8 qa0 = *(const bf8*)(Qrow0 + quad * 8);
    bf8 qa1 = *(const bf8*)(Qrow0 + 32 + quad * 8);
    bf8 qb0 = *(const bf8*)(Qrow1 + quad * 8);
    bf8 qb1 = *(const bf8*)(Qrow1 + 32 + quad * 8);
#pragma unroll
    for (int e = 0; e < 8; ++e) {
        qa0[e] = (bf16_t)((float)qa0[e] * 0.125f);
        qa1[e] = (bf16_t)((float)qa1[e] * 0.125f);
        qb0[e] = (bf16_t)((float)qb0[e] * 0.125f);
        qb1[e] = (bf16_t)((float)qb1[e] * 0.125f);
    }

    const bf16_t* Kg = K + head_off;
    const bf16_t* Vg = V + head_off;
    const int krow0 = t >> 3, kcol = (t & 7) * 8;   // K staging: coalesced rows
    // V staging: lane covers kv=lane for d-octets {wave, wave+4}; transposed
    // scalar writes hit banks 4e + (lane>>1): conflict-free.

    // ---- prologue: stage tile 0 into buf 0 ----
    uint4 kr0 = *(const uint4*)(Kg + (size_t)krow0 * NHD + kcol);
    uint4 kr1 = *(const uint4*)(Kg + (size_t)(krow0 + 32) * NHD + kcol);
    bf8  vr0 = *(const bf8*)(Vg + (size_t)lane * NHD + wave * 8);
    bf8  vr1 = *(const bf8*)(Vg + (size_t)lane * NHD + (wave + 4) * 8);
    *(uint4*)(&Ks[0][krow0 * 72 + kcol])        = kr0;
    *(uint4*)(&Ks[0][(krow0 + 32) * 72 + kcol]) = kr1;
#pragma unroll
    for (int e = 0; e < 8; ++e) {
        Vt[0][(wave * 8 + e) * 72 + lane]       = vr0[e];
        Vt[0][((wave + 4) * 8 + e) * 72 + lane] = vr1[e];
    }
    __syncthreads();

    f4 o0[4], o1[4];
    const f4 z = {0.f, 0.f, 0.f, 0.f};
#pragma unroll
    for (int i = 0; i < 4; ++i) { o0[i] = z; o1[i] = z; }
    float ls0[4] = {0.f, 0.f, 0.f, 0.f};
    float ls1[4] = {0.f, 0.f, 0.f, 0.f};

    bf16_t* Pw = &Ps[wave][0];
    const int pswz = (ln >> 2) << 3;       // read-side swizzle key

// one 16x64 strip: QK^T -> (mask) -> exp -> P roundtrip -> PV accumulate
#define DO_STRIP(QF0, QF1, OA, LS, DIAG, ROWB)                                        \
    {                                                                                 \
        f4 s[4];                                                                      \
        __builtin_amdgcn_s_setprio(1);                                                \
        _Pragma("unroll")                                                             \
        for (int nt = 0; nt < 4; ++nt) {                                              \
            const bf8 kf0 = *(const bf8*)(&KsB[(nt * 16 + ln) * 72 + quad * 8]);      \
            const bf8 kf1 = *(const bf8*)(&KsB[(nt * 16 + ln) * 72 + 32 + quad * 8]); \
            s[nt] = z;                                                                \
            s[nt] = __builtin_amdgcn_mfma_f32_16x16x32_bf16(QF0, kf0, s[nt], 0, 0, 0);\
            s[nt] = __builtin_amdgcn_mfma_f32_16x16x32_bf16(QF1, kf1, s[nt], 0, 0, 0);\
        }                                                                             \
        __builtin_amdgcn_s_setprio(0);                                                \
        if (DIAG) {                                                                   \
            const int rowg = (ROWB) + quad * 4;                                       \
            _Pragma("unroll")                                                         \
            for (int nt = 0; nt < 4; ++nt) {                                          \
                const int col = kv0 + nt * 16 + ln;                                   \
                _Pragma("unroll")                                                     \
                for (int r = 0; r < 4; ++r)                                           \
                    if (col > rowg + r) s[nt][r] = -1e30f;                            \
            }                                                                         \
        }                                                                             \
        _Pragma("unroll")                                                             \
        for (int nt = 0; nt < 4; ++nt)                                                \
            _Pragma("unroll")                                                         \
            for (int r = 0; r < 4; ++r) {                                             \
                const float p = __expf(s[nt][r]);                                     \
                s[nt][r] = p;                                                         \
                LS[r] += p;                                                           \
            }                                                                         \
        _Pragma("unroll")                                                             \
        for (int nt = 0; nt < 4; ++nt)                                                \
            _Pragma("unroll")                                                         \
            for (int r = 0; r < 4; ++r)                                               \
                Pw[(quad * 4 + r) * 72 + ((nt * 16 + ln) ^ (quad << 3))] =            \
                    (bf16_t)s[nt][r];                                                 \
        const bf8 p0 = *(const bf8*)(&Pw[ln * 72 + ((quad * 8) ^ pswz)]);             \
        const bf8 p1 = *(const bf8*)(&Pw[ln * 72 + 32 + ((quad * 8) ^ pswz)]);        \
        __builtin_amdgcn_s_setprio(1);                                                \
        _Pragma("unroll")                                                             \
        for (int dt = 0; dt < 4; ++dt) {                                              \
            const bf8 v0 = *(const bf8*)(&VtB[(dt * 16 + ln) * 72 + quad * 8]);       \
            const bf8 v1 = *(const bf8*)(&VtB[(dt * 16 + ln) * 72 + 32 + quad * 8]);  \
            OA[dt] = __builtin_amdgcn_mfma_f32_16x16x32_bf16(p0, v0, OA[dt], 0, 0, 0);\
            OA[dt] = __builtin_amdgcn_mfma_f32_16x16x32_bf16(p1, v1, OA[dt], 0, 0, 0);\
        }                                                                             \
        __builtin_amdgcn_s_setprio(0);                                                \
    }

#pragma unroll 1
    for (int j = 0; j <= jmax; ++j) {
        const bf16_t* KsB = &Ks[j & 1][0];
        const bf16_t* VtB = &Vt[j & 1][0];
        // ---- prefetch next tile into registers (lands under compute) ----
        if (j < jmax) {
            const size_t nb = (size_t)(j + 1) * 64;
            kr0 = *(const uint4*)(Kg + (nb + krow0) * NHD + kcol);
            kr1 = *(const uint4*)(Kg + (nb + krow0 + 32) * NHD + kcol);
            vr0 = *(const bf8*)(Vg + (nb + lane) * NHD + wave * 8);
            vr1 = *(const bf8*)(Vg + (nb + lane) * NHD + (wave + 4) * 8);
        }
        const int kv0 = j * 64;

        if (j <= j0max) DO_STRIP(qa0, qa1, o0, ls0, j == j0max, q0 + wave * 16);
        DO_STRIP(qb0, qb1, o1, ls1, j == jmax, q0 + 64 + wave * 16);

        // ---- commit prefetched tile to the other buffer (no pre-barrier:
        //      end-of-previous-iter barrier guarantees it is no longer read) ----
        if (j < jmax) {
            bf16_t* KsN = &Ks[(j + 1) & 1][0];
            bf16_t* VtN = &Vt[(j + 1) & 1][0];
            *(uint4*)(&KsN[krow0 * 72 + kcol])        = kr0;
            *(uint4*)(&KsN[(krow0 + 32) * 72 + kcol]) = kr1;
#pragma unroll
            for (int e = 0; e < 8; ++e) {
                VtN[(wave * 8 + e) * 72 + lane]       = vr0[e];
                VtN[((wave + 4) * 8 + e) * 72 + lane] = vr1[e];
            }
        }
        __syncthreads();
    }
#undef DO_STRIP

    // ---- epilogue: deferred row-sum reduce (16-lane groups), store both strips ----
#pragma unroll
    for (int off = 1; off < 16; off <<= 1)
#pragma unroll
        for (int r = 0; r < 4; ++r) {
            ls0[r] += __shfl_xor(ls0[r], off);
            ls1[r] += __shfl_xor(ls1[r], off);
        }

    const int b = h >> 4, hh = h & 15;
#pragma unroll
    for (int r = 0; r < 4; ++r) {
        const float inv0 = 1.f / ls0[r];
        const float inv1 = 1.f / ls1[r];
        const int gs0 = q0 + wave * 16 + quad * 4 + r;
        const int gs1 = gs0 + 64;
#pragma unroll
        for (int dt = 0; dt < 4; ++dt) {
            O[((size_t)(b * NS + gs0)) * ND + hh * NHD + dt * 16 + ln] = (bf16_t)(o0[dt][r] * inv0);
            O[((size_t)(b * NS + gs1)) * ND + hh * NHD + dt * 16 + ln] = (bf16_t)(o1[dt][r] * inv1);
        }
    }
}

// ---------------- output projection GEMM (m97 structure) ----------------
__global__ __launch_bounds__(256) void gemm_proj(const bf16_t* __restrict__ A,
                                                 const bf16_t* __restrict__ Bw,
                                                 const float* __restrict__ bo,
                                                 const float* __restrict__ comp,
                                                 float* __restrict__ out) {
    __shared__ __align__(16) bf16_t As[128 * 32];
    __shared__ __align__(16) bf16_t Bs[128 * 32];
    const int t = threadIdx.x;
    const int wave = t >> 6, lane = t & 63, ln = lane & 15, quad = lane >> 4;
    const int wm = (wave >> 1) * 64, wn = (wave & 1) * 64;
    const int m0 = blockIdx.y * 128, n0 = blockIdx.x * 128;
    const int K = 1024;

    f4 acc[4][4];
    const f4 z = {0.f, 0.f, 0.f, 0.f};
#pragma unroll
    for (int i = 0; i < 4; ++i)
#pragma unroll
        for (int j = 0; j < 4; ++j) acc[i][j] = z;

    const int srow = wave * 16 + (lane >> 2);
    const int scol = (lane & 3) * 8;
    const bf16_t* Ag0 = A  + (size_t)(m0 + srow) * K + scol;
    const bf16_t* Ag1 = A  + (size_t)(m0 + srow + 64) * K + scol;
    const bf16_t* Bg0 = Bw + (size_t)(n0 + srow) * K + scol;
    const bf16_t* Bg1 = Bw + (size_t)(n0 + srow + 64) * K + scol;
    bf16_t* Al0 = &As[srow * 32 + scol];
    bf16_t* Al1 = &As[(srow + 64) * 32 + scol];
    bf16_t* Bl0 = &Bs[srow * 32 + scol];
    bf16_t* Bl1 = &Bs[(srow + 64) * 32 + scol];

    for (int k0 = 0; k0 < K; k0 += 32) {
        __syncthreads();
        GLDS16(Ag0 + k0, Al0);
        GLDS16(Ag1 + k0, Al1);
        GLDS16(Bg0 + k0, Bl0);
        GLDS16(Bg1 + k0, Bl1);
        __syncthreads();
        bf8 af[4], bfr[4];
#pragma unroll
        for (int mt = 0; mt < 4; ++mt) af[mt]  = *(const bf8*)(&As[(wm + mt * 16 + ln) * 32 + quad * 8]);
#pragma unroll
        for (int nt = 0; nt < 4; ++nt) bfr[nt] = *(const bf8*)(&Bs[(wn + nt * 16 + ln) * 32 + quad * 8]);
#pragma unroll
        for (int mt = 0; mt < 4; ++mt)
#pragma unroll
            for (int nt = 0; nt < 4; ++nt)
                acc[mt][nt] = __builtin_amdgcn_mfma_f32_16x16x32_bf16(af[mt], bfr[nt], acc[mt][nt], 0, 0, 0);
    }

#pragma unroll
    for (int nt = 0; nt < 4; ++nt) {
        const int gn = n0 + wn + nt * 16 + ln;
        const float bias = bo[gn] + comp[gn];
#pragma unroll
        for (int mt = 0; mt < 4; ++mt) {
#pragma unroll
            for (int r = 0; r < 4; ++r) {
                const int gm = m0 + wm + mt * 16 + quad * 4 + r;
                out[(size_t)gm * ND + gn] = acc[mt][nt][r] + bias;
            }
        }
    }
}

extern "C" void kernel_launch(void* const* d_in, const int* in_sizes, int n_in,
                              void* d_out, int out_size, void* d_ws, size_t ws_size,
                              hipStream_t stream) {
    const float* x    = (const float*)d_in[0];
    const float* Wq   = (const float*)d_in[1];
    const float* bq   = (const float*)d_in[2];
    const float* Wk   = (const float*)d_in[3];
    const float* bk   = (const float*)d_in[4];
    const float* Wv   = (const float*)d_in[5];
    const float* bv   = (const float*)d_in[6];
    const float* Wo   = (const float*)d_in[7];
    const float* bo   = (const float*)d_in[8];
    const float* comp = (const float*)d_in[9];
    float* out = (float*)d_out;

    char* w = (char*)d_ws;
    bf16_t* Xb   = (bf16_t*)(w);                         // 8192x1024
    bf16_t* Wqkv = (bf16_t*)(w + 16777216);              // 3072x1024
    bf16_t* Wob  = (bf16_t*)(w + 23068672);              // 1024x1024
    bf16_t* Qh   = (bf16_t*)(w + 25165824);              // [B,H,S,hd]
    bf16_t* Kh   = (bf16_t*)(w + 41943040);
    bf16_t* Vh   = (bf16_t*)(w + 58720256);
    bf16_t* AOb  = (bf16_t*)(w + 75497472);              // 8192x1024

    cvt_all<<<12288, 256, 0, stream>>>(x, Wq, Wk, Wv, Wo, Xb, Wqkv, Wob);
    gemm_qkv<<<dim3(3072 / 128, NM / 128), 256, 0, stream>>>(Xb, Wqkv, bq, bk, bv, Qh, Kh, Vh);
    attn_kernel<<<1024, 256, 0, stream>>>(Qh, Kh, Vh, AOb);
    gemm_proj<<<dim3(1024 / 128, NM / 128), 256, 0, stream>>>(AOb, Wob, bo, comp, out);
}

// Round 7
// 281.369 us; speedup vs baseline: 1.1224x; 1.1224x over previous
//
#include <hip/hip_runtime.h>
#include <hip/hip_bf16.h>

#define NB 4
#define NS 2048
#define ND 1024
#define NH 16
#define NHD 64
#define NM (NB*NS)   // 8192 rows of X

typedef __bf16 bf16_t;
typedef bf16_t bf8  __attribute__((ext_vector_type(8)));
typedef bf16_t bf4v __attribute__((ext_vector_type(4)));
typedef float  f4   __attribute__((ext_vector_type(4)));

// async global -> LDS, 16B per lane (dest = wave-uniform base + lane*16)
#define GLDS16(g, l) __builtin_amdgcn_global_load_lds( \
    (const __attribute__((address_space(1))) void*)(g), \
    (__attribute__((address_space(3))) void*)(l), 16, 0, 0)

// ---------------- fused fp32 -> bf16 conversion (X + 4 weights, one launch) ----
__global__ __launch_bounds__(256) void cvt_all(const float* __restrict__ x,
                                               const float* __restrict__ wq,
                                               const float* __restrict__ wk,
                                               const float* __restrict__ wv,
                                               const float* __restrict__ wo,
                                               bf16_t* __restrict__ Xb,
                                               bf16_t* __restrict__ Wqkv,
                                               bf16_t* __restrict__ Wob) {
    const int i = blockIdx.x * 256 + threadIdx.x;   // float4 index, total 3145728
    const float* src;
    bf16_t* dst;
    int off;
    if (i < 2097152) {            // X: 8192*1024 floats = 2097152 float4
        src = x; dst = Xb; off = i;
    } else {
        const int j = i - 2097152;        // [0, 4*262144)
        const int w = j >> 18;            // which weight
        off = j & 262143;
        src = (w == 0 ? wq : w == 1 ? wk : w == 2 ? wv : wo);
        dst = (w == 3 ? Wob : Wqkv + ((size_t)w << 20));
    }
    const float4 v = ((const float4*)src)[off];
    bf4v o;
    o[0] = (bf16_t)v.x; o[1] = (bf16_t)v.y; o[2] = (bf16_t)v.z; o[3] = (bf16_t)v.w;
    ((bf4v*)dst)[off] = o;
}

// ---------------- fused QKV GEMM (m97 structure: linear LDS + global_load_lds) ----
__global__ __launch_bounds__(256) void gemm_qkv(const bf16_t* __restrict__ A,
                                                const bf16_t* __restrict__ Bw,
                                                const float* __restrict__ bq,
                                                const float* __restrict__ bk,
                                                const float* __restrict__ bv,
                                                bf16_t* __restrict__ Qh,
                                                bf16_t* __restrict__ Kh,
                                                bf16_t* __restrict__ Vh) {
    __shared__ __align__(16) bf16_t As[128 * 32];
    __shared__ __align__(16) bf16_t Bs[128 * 32];
    const int t = threadIdx.x;
    const int wave = t >> 6, lane = t & 63, ln = lane & 15, quad = lane >> 4;
    const int wm = (wave >> 1) * 64, wn = (wave & 1) * 64;
    const int m0 = blockIdx.y * 128, n0 = blockIdx.x * 128;
    const int K = 1024;

    f4 acc[4][4];
    const f4 z = {0.f, 0.f, 0.f, 0.f};
#pragma unroll
    for (int i = 0; i < 4; ++i)
#pragma unroll
        for (int j = 0; j < 4; ++j) acc[i][j] = z;

    const int srow = wave * 16 + (lane >> 2);
    const int scol = (lane & 3) * 8;
    const bf16_t* Ag0 = A  + (size_t)(m0 + srow) * K + scol;
    const bf16_t* Ag1 = A  + (size_t)(m0 + srow + 64) * K + scol;
    const bf16_t* Bg0 = Bw + (size_t)(n0 + srow) * K + scol;
    const bf16_t* Bg1 = Bw + (size_t)(n0 + srow + 64) * K + scol;
    bf16_t* Al0 = &As[srow * 32 + scol];
    bf16_t* Al1 = &As[(srow + 64) * 32 + scol];
    bf16_t* Bl0 = &Bs[srow * 32 + scol];
    bf16_t* Bl1 = &Bs[(srow + 64) * 32 + scol];

    for (int k0 = 0; k0 < K; k0 += 32) {
        __syncthreads();
        GLDS16(Ag0 + k0, Al0);
        GLDS16(Ag1 + k0, Al1);
        GLDS16(Bg0 + k0, Bl0);
        GLDS16(Bg1 + k0, Bl1);
        __syncthreads();
        bf8 af[4], bfr[4];
#pragma unroll
        for (int mt = 0; mt < 4; ++mt) af[mt]  = *(const bf8*)(&As[(wm + mt * 16 + ln) * 32 + quad * 8]);
#pragma unroll
        for (int nt = 0; nt < 4; ++nt) bfr[nt] = *(const bf8*)(&Bs[(wn + nt * 16 + ln) * 32 + quad * 8]);
#pragma unroll
        for (int mt = 0; mt < 4; ++mt)
#pragma unroll
            for (int nt = 0; nt < 4; ++nt)
                acc[mt][nt] = __builtin_amdgcn_mfma_f32_16x16x32_bf16(af[mt], bfr[nt], acc[mt][nt], 0, 0, 0);
    }

#pragma unroll
    for (int nt = 0; nt < 4; ++nt) {
        const int gn = n0 + wn + nt * 16 + ln;
        const int sec = gn >> 10, nn = gn & 1023;
        const int h = nn >> 6, d = nn & 63;
        const float bias = (sec == 0 ? bq[nn] : (sec == 1 ? bk[nn] : bv[nn]));
        bf16_t* dstBase = (sec == 0 ? Qh : (sec == 1 ? Kh : Vh));
#pragma unroll
        for (int mt = 0; mt < 4; ++mt) {
#pragma unroll
            for (int r = 0; r < 4; ++r) {
                const int gm = m0 + wm + mt * 16 + quad * 4 + r;
                const int b = gm >> 11, s = gm & 2047;
                dstBase[((size_t)(b * NH + h) * NS + s) * NHD + d] = (bf16_t)(acc[mt][nt][r] + bias);
            }
        }
    }
}

// ---------------- flash attention ----------------
// v6b = v4 geometry (2048 blocks x 4 waves, 27 KB LDS, single-buffer staging,
// 2 barriers/iter) + SWAPPED QK^T: mfma(K,Q) makes each lane own q-row ln
// (kv = nt*16+quad*4+r). P->LDS becomes 4 ds_write_b64 (was 16 b16), row-sum
// is one scalar/lane. Explicit lgkm fence kept on the P roundtrip (defensive:
// vector-type-punned write->read on same bytes; rule-18 discipline).
// Inherited: XCD head mapping, LPT, fixed m=0 softmax with deferred sums,
// conflict-free transposed V staging, reg prefetch, setprio on MFMA clusters.
__global__ __launch_bounds__(256) void attn_kernel(const bf16_t* __restrict__ Q,
                                                   const bf16_t* __restrict__ K,
                                                   const bf16_t* __restrict__ V,
                                                   bf16_t* __restrict__ O) {
    __shared__ __align__(16) bf16_t Ks[64 * 72];       // [kv][d], padded
    __shared__ __align__(16) bf16_t Vt[64 * 72];       // [d][kv], padded
    __shared__ __align__(16) bf16_t Ps[4][16 * 72];    // per-wave P strip [q=ln][kv]
    const int L = blockIdx.x;
    const int mm = L >> 3;
    const int h  = ((mm >> 5) << 3) | (L & 7);         // head 0..63; XCD = L&7
    const int qt = 31 - (mm & 31);                     // LPT: longest first
    const int q0 = qt * 64;
    const int jmax = qt;
    const size_t head_off = (size_t)h * NS * NHD;
    const int t = threadIdx.x;
    const int wave = t >> 6, lane = t & 63, ln = lane & 15, quad = lane >> 4;

    // per-wave Q strip fragments, 1/sqrt(hd)=0.125 folded in (exact in bf16)
    const bf16_t* Qrow = Q + head_off + (size_t)(q0 + wave * 16 + ln) * NHD;
    bf8 qf0 = *(const bf8*)(Qrow + quad * 8);
    bf8 qf1 = *(const bf8*)(Qrow + 32 + quad * 8);
#pragma unroll
    for (int e = 0; e < 8; ++e) {
        qf0[e] = (bf16_t)((float)qf0[e] * 0.125f);
        qf1[e] = (bf16_t)((float)qf1[e] * 0.125f);
    }

    const bf16_t* Kg = K + head_off;
    const bf16_t* Vg = V + head_off;
    const int krow0 = t >> 3, kcol = (t & 7) * 8;   // K staging: coalesced rows
    // V staging: lane covers kv=lane for d-octets {wave, wave+4}; transposed
    // scalar writes hit banks 4e + (lane>>1): conflict-free.

    // ---- prologue: stage tile 0 ----
    uint4 kr0 = *(const uint4*)(Kg + (size_t)krow0 * NHD + kcol);
    uint4 kr1 = *(const uint4*)(Kg + (size_t)(krow0 + 32) * NHD + kcol);
    bf8  vr0 = *(const bf8*)(Vg + (size_t)lane * NHD + wave * 8);
    bf8  vr1 = *(const bf8*)(Vg + (size_t)lane * NHD + (wave + 4) * 8);
    *(uint4*)(&Ks[krow0 * 72 + kcol])        = kr0;
    *(uint4*)(&Ks[(krow0 + 32) * 72 + kcol]) = kr1;
#pragma unroll
    for (int e = 0; e < 8; ++e) {
        Vt[(wave * 8 + e) * 72 + lane]       = vr0[e];
        Vt[((wave + 4) * 8 + e) * 72 + lane] = vr1[e];
    }
    __syncthreads();

    f4 o[4];
    const f4 z = {0.f, 0.f, 0.f, 0.f};
#pragma unroll
    for (int i = 0; i < 4; ++i) o[i] = z;
    float ls = 0.f;                        // per-lane partial sum of row q=ln

    bf16_t* Pw = &Ps[wave][0];

#pragma unroll 1
    for (int j = 0; j <= jmax; ++j) {
        // ---- prefetch next tile into registers (lands under compute) ----
        if (j < jmax) {
            const size_t nb = (size_t)(j + 1) * 64;
            kr0 = *(const uint4*)(Kg + (nb + krow0) * NHD + kcol);
            kr1 = *(const uint4*)(Kg + (nb + krow0 + 32) * NHD + kcol);
            vr0 = *(const bf8*)(Vg + (nb + lane) * NHD + wave * 8);
            vr1 = *(const bf8*)(Vg + (nb + lane) * NHD + (wave + 4) * 8);
        }

        // ---- S^T = K @ Q^T (swapped): lane owns q-row ln ----
        // s[nt][r] = S[q = q0+wave*16+ln][kv = j*64 + nt*16 + quad*4 + r]
        f4 s[4];
        __builtin_amdgcn_s_setprio(1);
#pragma unroll
        for (int nt = 0; nt < 4; ++nt) {
            const bf8 kf0 = *(const bf8*)(&Ks[(nt * 16 + ln) * 72 + quad * 8]);
            const bf8 kf1 = *(const bf8*)(&Ks[(nt * 16 + ln) * 72 + 32 + quad * 8]);
            s[nt] = z;
            s[nt] = __builtin_amdgcn_mfma_f32_16x16x32_bf16(kf0, qf0, s[nt], 0, 0, 0);
            s[nt] = __builtin_amdgcn_mfma_f32_16x16x32_bf16(kf1, qf1, s[nt], 0, 0, 0);
        }
        __builtin_amdgcn_s_setprio(0);

        // ---- causal mask (diagonal tile only; block-uniform branch) ----
        if (j == jmax) {
            const int kv0 = j * 64;
            const int rowq = q0 + wave * 16 + ln;
#pragma unroll
            for (int nt = 0; nt < 4; ++nt) {
#pragma unroll
                for (int r = 0; r < 4; ++r)
                    if (kv0 + nt * 16 + quad * 4 + r > rowq) s[nt][r] = -1e30f;
            }
        }

        // ---- p = exp(s) (m fixed at 0), per-lane scalar partial sum ----
#pragma unroll
        for (int nt = 0; nt < 4; ++nt)
#pragma unroll
            for (int r = 0; r < 4; ++r) {
                const float p = __expf(s[nt][r]);
                s[nt][r] = p;
                ls += p;
            }

        // ---- P -> wave-private LDS strip: 4x ds_write_b64, row = ln ----
#pragma unroll
        for (int nt = 0; nt < 4; ++nt) {
            bf4v pk;
#pragma unroll
            for (int r = 0; r < 4; ++r) pk[r] = (bf16_t)s[nt][r];
            *(bf4v*)(&Pw[ln * 72 + nt * 16 + quad * 4]) = pk;
        }
        // defensive fence: wave-private write->read of same bytes through
        // different vector types; make the ordering explicit (rule 18).
        asm volatile("s_waitcnt lgkmcnt(0)" ::: "memory");
        __builtin_amdgcn_sched_barrier(0);
        const bf8 p0 = *(const bf8*)(&Pw[ln * 72 + quad * 8]);
        const bf8 p1 = *(const bf8*)(&Pw[ln * 72 + 32 + quad * 8]);

        // ---- O += P @ V ----
        __builtin_amdgcn_s_setprio(1);
#pragma unroll
        for (int dt = 0; dt < 4; ++dt) {
            const bf8 v0 = *(const bf8*)(&Vt[(dt * 16 + ln) * 72 + quad * 8]);
            const bf8 v1 = *(const bf8*)(&Vt[(dt * 16 + ln) * 72 + 32 + quad * 8]);
            o[dt] = __builtin_amdgcn_mfma_f32_16x16x32_bf16(p0, v0, o[dt], 0, 0, 0);
            o[dt] = __builtin_amdgcn_mfma_f32_16x16x32_bf16(p1, v1, o[dt], 0, 0, 0);
        }
        __builtin_amdgcn_s_setprio(0);

        // ---- commit prefetched tile to LDS ----
        if (j < jmax) {
            __syncthreads();
            *(uint4*)(&Ks[krow0 * 72 + kcol])        = kr0;
            *(uint4*)(&Ks[(krow0 + 32) * 72 + kcol]) = kr1;
#pragma unroll
            for (int e = 0; e < 8; ++e) {
                Vt[(wave * 8 + e) * 72 + lane]       = vr0[e];
                Vt[((wave + 4) * 8 + e) * 72 + lane] = vr1[e];
            }
            __syncthreads();
        }
    }

    // ---- epilogue: complete row sums (quads hold disjoint kv subsets) ----
    ls += __shfl_xor(ls, 16);
    ls += __shfl_xor(ls, 32);   // now every lane has the full sum of row q=ln

    const int b = h >> 4, hh = h & 15;
#pragma unroll
    for (int r = 0; r < 4; ++r) {
        // output row of this lane is quad*4+r; its sum lives on lane quad*4+r
        const float inv = 1.f / __shfl(ls, quad * 4 + r);
        const int gs = q0 + wave * 16 + quad * 4 + r;
#pragma unroll
        for (int dt = 0; dt < 4; ++dt)
            O[((size_t)(b * NS + gs)) * ND + hh * NHD + dt * 16 + ln] = (bf16_t)(o[dt][r] * inv);
    }
}

// ---------------- output projection GEMM (m97 structure) ----------------
__global__ __launch_bounds__(256) void gemm_proj(const bf16_t* __restrict__ A,
                                                 const bf16_t* __restrict__ Bw,
                                                 const float* __restrict__ bo,
                                                 const float* __restrict__ comp,
                                                 float* __restrict__ out) {
    __shared__ __align__(16) bf16_t As[128 * 32];
    __shared__ __align__(16) bf16_t Bs[128 * 32];
    const int t = threadIdx.x;
    const int wave = t >> 6, lane = t & 63, ln = lane & 15, quad = lane >> 4;
    const int wm = (wave >> 1) * 64, wn = (wave & 1) * 64;
    const int m0 = blockIdx.y * 128, n0 = blockIdx.x * 128;
    const int K = 1024;

    f4 acc[4][4];
    const f4 z = {0.f, 0.f, 0.f, 0.f};
#pragma unroll
    for (int i = 0; i < 4; ++i)
#pragma unroll
        for (int j = 0; j < 4; ++j) acc[i][j] = z;

    const int srow = wave * 16 + (lane >> 2);
    const int scol = (lane & 3) * 8;
    const bf16_t* Ag0 = A  + (size_t)(m0 + srow) * K + scol;
    const bf16_t* Ag1 = A  + (size_t)(m0 + srow + 64) * K + scol;
    const bf16_t* Bg0 = Bw + (size_t)(n0 + srow) * K + scol;
    const bf16_t* Bg1 = Bw + (size_t)(n0 + srow + 64) * K + scol;
    bf16_t* Al0 = &As[srow * 32 + scol];
    bf16_t* Al1 = &As[(srow + 64) * 32 + scol];
    bf16_t* Bl0 = &Bs[srow * 32 + scol];
    bf16_t* Bl1 = &Bs[(srow + 64) * 32 + scol];

    for (int k0 = 0; k0 < K; k0 += 32) {
        __syncthreads();
        GLDS16(Ag0 + k0, Al0);
        GLDS16(Ag1 + k0, Al1);
        GLDS16(Bg0 + k0, Bl0);
        GLDS16(Bg1 + k0, Bl1);
        __syncthreads();
        bf8 af[4], bfr[4];
#pragma unroll
        for (int mt = 0; mt < 4; ++mt) af[mt]  = *(const bf8*)(&As[(wm + mt * 16 + ln) * 32 + quad * 8]);
#pragma unroll
        for (int nt = 0; nt < 4; ++nt) bfr[nt] = *(const bf8*)(&Bs[(wn + nt * 16 + ln) * 32 + quad * 8]);
#pragma unroll
        for (int mt = 0; mt < 4; ++mt)
#pragma unroll
            for (int nt = 0; nt < 4; ++nt)
                acc[mt][nt] = __builtin_amdgcn_mfma_f32_16x16x32_bf16(af[mt], bfr[nt], acc[mt][nt], 0, 0, 0);
    }

#pragma unroll
    for (int nt = 0; nt < 4; ++nt) {
        const int gn = n0 + wn + nt * 16 + ln;
        const float bias = bo[gn] + comp[gn];
#pragma unroll
        for (int mt = 0; mt < 4; ++mt) {
#pragma unroll
            for (int r = 0; r < 4; ++r) {
                const int gm = m0 + wm + mt * 16 + quad * 4 + r;
                out[(size_t)gm * ND + gn] = acc[mt][nt][r] + bias;
            }
        }
    }
}

extern "C" void kernel_launch(void* const* d_in, const int* in_sizes, int n_in,
                              void* d_out, int out_size, void* d_ws, size_t ws_size,
                              hipStream_t stream) {
    const float* x    = (const float*)d_in[0];
    const float* Wq   = (const float*)d_in[1];
    const float* bq   = (const float*)d_in[2];
    const float* Wk   = (const float*)d_in[3];
    const float* bk   = (const float*)d_in[4];
    const float* Wv   = (const float*)d_in[5];
    const float* bv   = (const float*)d_in[6];
    const float* Wo   = (const float*)d_in[7];
    const float* bo   = (const float*)d_in[8];
    const float* comp = (const float*)d_in[9];
    float* out = (float*)d_out;

    char* w = (char*)d_ws;
    bf16_t* Xb   = (bf16_t*)(w);                         // 8192x1024
    bf16_t* Wqkv = (bf16_t*)(w + 16777216);              // 3072x1024
    bf16_t* Wob  = (bf16_t*)(w + 23068672);              // 1024x1024
    bf16_t* Qh   = (bf16_t*)(w + 25165824);              // [B,H,S,hd]
    bf16_t* Kh   = (bf16_t*)(w + 41943040);
    bf16_t* Vh   = (bf16_t*)(w + 58720256);
    bf16_t* AOb  = (bf16_t*)(w + 75497472);              // 8192x1024

    cvt_all<<<12288, 256, 0, stream>>>(x, Wq, Wk, Wv, Wo, Xb, Wqkv, Wob);
    gemm_qkv<<<dim3(3072 / 128, NM / 128), 256, 0, stream>>>(Xb, Wqkv, bq, bk, bv, Qh, Kh, Vh);
    attn_kernel<<<2048, 256, 0, stream>>>(Qh, Kh, Vh, AOb);
    gemm_proj<<<dim3(1024 / 128, NM / 128), 256, 0, stream>>>(AOb, Wob, bo, comp, out);
}